// Round 16
// baseline (237.169 us; speedup 1.0000x reference)
//
#include <hip/hip_runtime.h>
#include <cstdint>

#define NB 8
#define NC 256
#define NN 2304           // H*W
#define NM (NB*NN)        // 18432
#define EPS_ 1e-5f
#define LOG2E_ 1.44269504088896f

typedef __attribute__((ext_vector_type(8))) short bf16x8;
typedef __attribute__((ext_vector_type(8))) _Float16 f16x8;
typedef __attribute__((ext_vector_type(4))) _Float16 f16x4;
typedef __attribute__((ext_vector_type(4))) float f32x4;

__device__ __forceinline__ short f2bf(float x) {
    union { float f; uint32_t u; } v; v.f = x;
    uint32_t r = v.u + 0x7fffu + ((v.u >> 16) & 1u);   // RNE
    return (short)(r >> 16);
}

#define MFMA_BF(a,b,c)  __builtin_amdgcn_mfma_f32_16x16x32_bf16(a,b,c,0,0,0)
#define MFMA_F16(a,b,c) __builtin_amdgcn_mfma_f32_16x16x32_f16(a,b,c,0,0,0)

// async global->LDS, 16B per lane; lds ptr must be wave-uniform base
#define GLOAD16(g,l) __builtin_amdgcn_global_load_lds( \
    (__attribute__((address_space(1))) void*)(g), \
    (__attribute__((address_space(3))) void*)(l), 16, 0, 0)

// counted-vmcnt barrier pair (r7-verified machinery): leave newest N in flight
#define WAITV4_BAR()  do { asm volatile("s_waitcnt vmcnt(4)" ::: "memory"); \
    __builtin_amdgcn_sched_barrier(0); __builtin_amdgcn_s_barrier(); \
    __builtin_amdgcn_sched_barrier(0); } while (0)
#define WAITV0_BAR()  do { asm volatile("s_waitcnt vmcnt(0)" ::: "memory"); \
    __builtin_amdgcn_sched_barrier(0); __builtin_amdgcn_s_barrier(); \
    __builtin_amdgcn_sched_barrier(0); } while (0)
#define PLAIN_BAR()   do { __builtin_amdgcn_sched_barrier(0); \
    __builtin_amdgcn_s_barrier(); __builtin_amdgcn_sched_barrier(0); } while (0)

// ---------------------------------------------------------------------------
// K_head: fused independent preprocessing (one dispatch, flat grid):
//   blocks [0, 9216)        : xpose_cast  (x f32 -> Xcat bf16 + Xbn f16)
//   blocks [9216, 12288)    : prepack     (weights -> Wcat bf16, biasc)
//   blocks [12288, 12360)   : zero rowsum (replay-safe)
// ---------------------------------------------------------------------------
__global__ __launch_bounds__(256) void head_kernel(
    const float* __restrict__ xr, const float* __restrict__ xi,
    const float* __restrict__ q_wr, const float* __restrict__ q_wi,
    const float* __restrict__ q_br, const float* __restrict__ q_bi,
    const float* __restrict__ k_wr, const float* __restrict__ k_wi,
    const float* __restrict__ k_br, const float* __restrict__ k_bi,
    const float* __restrict__ v_wr, const float* __restrict__ v_wi,
    const float* __restrict__ v_br, const float* __restrict__ v_bi,
    short* __restrict__ Wcat, float* __restrict__ biasc,
    short* __restrict__ Xcat, _Float16* __restrict__ Xbn,
    float* __restrict__ rowsum)
{
    __shared__ float t[32][33];
    int bid = blockIdx.x;
    int tid = threadIdx.x;
    if (bid < 9216) {
        int bx = bid % 72, rest = bid / 72;
        int by = rest & 7, bz = rest >> 3;
        int ri = bz & 1, b = bz >> 1;
        const float* src = (ri ? xi : xr) + (size_t)b * NC * NN;
        _Float16* xbdst = Xbn + (size_t)(ri * NB + b) * NC * NN;
        int n0 = bx * 32, c0 = by * 32;
        int tx = tid & 31, ty = tid >> 5;       // (32, 8)
        #pragma unroll
        for (int i = 0; i < 4; i++) {
            int c = c0 + ty + i*8;
            float v = src[(size_t)c * NN + n0 + tx];
            t[ty + i*8][tx] = v;
            xbdst[(size_t)c * NN + n0 + tx] = (_Float16)v;
        }
        __syncthreads();
        #pragma unroll
        for (int i = 0; i < 4; i++) {
            int n = n0 + ty + i*8;
            Xcat[(size_t)(b * NN + n) * 512 + ri * 256 + c0 + tx] = f2bf(t[tx][ty + i*8]);
        }
    } else if (bid < 12288) {
        int idx = (bid - 9216) * 256 + tid;     // < 786432
        int g    = idx >> 17;
        int r    = idx & 131071;
        int d    = r >> 9;
        int k    = r & 511;
        int half = k >> 8;
        int kk   = k & 255;
        const float* wr_ = (g < 2) ? q_wr : (g < 4) ? k_wr : v_wr;
        const float* wi_ = (g < 2) ? q_wi : (g < 4) ? k_wi : v_wi;
        bool isR = (g & 1) == 0;
        const float* src = (half == 0) ? (isR ? wr_ : wi_) : (isR ? wi_ : wr_);
        float sign  = (half == 1 && isR) ? -1.f : 1.f;
        float scale = (g < 2) ? 0.0625f : 1.f;
        Wcat[idx] = f2bf(sign * scale * src[d * 256 + kk]);
        if (idx < 1536) {
            int gg = idx >> 8, dd = idx & 255;
            const float* bsrc = (gg==0)?q_br:(gg==1)?q_bi:(gg==2)?k_br:(gg==3)?k_bi:(gg==4)?v_br:v_bi;
            biasc[idx] = bsrc[dd] * ((gg < 2) ? 0.0625f : 1.f);
        }
    } else {
        int i = (bid - 12288) * 256 + tid;
        if (i < NM) rowsum[i] = 0.f;
    }
}

// ---------------------------------------------------------------------------
// K2: QKV GEMM [M x 512] @ [512 x 1536], m97 structure + involution swizzle
// (conflicts=0). launch_bounds (256,3) — verified no-spill config.
// ---------------------------------------------------------------------------
__global__ __launch_bounds__(256, 3) void qkv_gemm(
    const short* __restrict__ Xcat, const short* __restrict__ Wcat,
    const float* __restrict__ biasc,
    short* __restrict__ QK, short* __restrict__ Vt)
{
    __shared__ short ldsA[128*64];
    __shared__ short ldsB[128*64];
    int tm = blockIdx.x;                 // 0..143 (M tiles)
    int tn = blockIdx.y;                 // 0..11  (N tiles)
    const short* Apanel = Xcat + (size_t)tm * 128 * 512;
    const short* Bpanel = Wcat + (size_t)tn * 128 * 512;
    int tid  = threadIdx.x;
    int lane = tid & 63, wid = tid >> 6;
    int li = lane & 15, lg = lane >> 4;
    int wr = wid >> 1, wc = wid & 1;
    int srow = tid >> 3, schk = tid & 7;
    int gsl = (schk ^ (srow & 7)) * 8;   // pre-swizzled global source slot

    f32x4 acc[4][4];
    #pragma unroll
    for (int i = 0; i < 4; i++)
        #pragma unroll
        for (int j = 0; j < 4; j++) acc[i][j] = (f32x4){0.f,0.f,0.f,0.f};

    for (int ks0 = 0; ks0 < 8; ks0++) {
        #pragma unroll
        for (int j = 0; j < 4; j++) {
            const short* ga = Apanel + (size_t)(j*32 + srow)*512 + ks0*64 + gsl;
            const short* gb = Bpanel + (size_t)(j*32 + srow)*512 + ks0*64 + gsl;
            GLOAD16(ga, ldsA + j*2048 + wid*512);
            GLOAD16(gb, ldsB + j*2048 + wid*512);
        }
        __syncthreads();
        #pragma unroll
        for (int ks = 0; ks < 2; ks++) {
            int so = ((ks*4 + lg) ^ (li & 7)) * 8;   // swizzled read slot
            bf16x8 a[4], bv[4];
            #pragma unroll
            for (int i = 0; i < 4; i++) {
                a[i]  = *(const bf16x8*)&ldsA[(wr*64 + i*16 + li)*64 + so];
                bv[i] = *(const bf16x8*)&ldsB[(wc*64 + i*16 + li)*64 + so];
            }
            #pragma unroll
            for (int i = 0; i < 4; i++)
                #pragma unroll
                for (int j = 0; j < 4; j++)
                    acc[i][j] = MFMA_BF(a[i], bv[j], acc[i][j]);
        }
        __syncthreads();
    }

    if (tn < 8) {
        #pragma unroll
        for (int bj = 0; bj < 4; bj++) {
            int ncol = tn*128 + wc*64 + bj*16 + li;
            float bias = biasc[ncol];
            #pragma unroll
            for (int ai = 0; ai < 4; ai++)
                #pragma unroll
                for (int rr = 0; rr < 4; rr++) {
                    int m = tm*128 + wr*64 + ai*16 + lg*4 + rr;
                    QK[(size_t)m * 1024 + ncol] = f2bf(acc[ai][bj][rr] + bias);
                }
        }
    } else {
        int b  = tm / 18;
        int n0 = (tm - b*18) * 128 + wr*64;
        #pragma unroll
        for (int bj = 0; bj < 4; bj++) {
            int ncol = tn*128 + wc*64 + bj*16 + li;
            int cc = ncol - 1024;        // 0..511
            int ri2 = cc >> 8, c = cc & 255;
            float bias = biasc[ncol];
            short* vrow = Vt + ((size_t)((ri2*NB + b)*NC + c))*NN + n0;
            #pragma unroll
            for (int ai = 0; ai < 4; ai++) {
                f16x4 pk;
                #pragma unroll
                for (int rr = 0; rr < 4; rr++) pk[rr] = (_Float16)(acc[ai][bj][rr] + bias);
                *(f16x4*)(vrow + ai*16 + lg*4) = pk;
            }
        }
    }
}

// ---------------------------------------------------------------------------
// K3a: P' = exp(Q K^T - 8) + rowsum atomics.  REDESIGNED this round:
// K=512 fits in registers -> A (Q-panel) preloaded (16 bf16x8 = 64 VGPR,
// round-1-verified pattern); only B (K-panel) staged through LDS, DOUBLE-
// buffered (2x16KB = 32KB, keeps 3 blocks/CU) with counted-vmcnt pipeline
// (r7-verified): stage(next) -> vmcnt(4)+barrier (cur's loads had a full
// compute phase to land) -> compute -> plain barrier. vmcnt(0) only at kt=7.
// Wave tile 16 q-rows x 128 kv-cols; block = 4 waves = 64x128; grid 36*18*8.
// kt loop fully unrolled so qf[] indexing is compile-time (no scratch).
// ---------------------------------------------------------------------------
__global__ __launch_bounds__(256, 3) void qk_gemm(
    const short* __restrict__ QK, _Float16* __restrict__ S,
    float* __restrict__ rowsum)
{
    __shared__ short B0[128*64];
    __shared__ short B1[128*64];
    int bi = blockIdx.x;
    int b  = bi & 7;                     // XCD pin
    int t  = bi >> 3;
    int tm = t % 36, tn = t / 36;        // tm: 64-row q tile; tn: 128-col kv tile
    const short* Bbase = QK + ((size_t)b*NN + tn*128)*1024 + 512;  // K cols
    int tid  = threadIdx.x;
    int lane = tid & 63, wid = tid >> 6;
    int li = lane & 15, lg = lane >> 4;
    int srow = tid >> 3, schk = tid & 7;
    int gsl = (schk ^ (srow & 7)) * 8;   // pre-swizzled global source slot

    // A (Q) preload: wave wid owns rows tm*64 + wid*16 + li; k = ks*32 + lg*8
    const short* qrow = QK + ((size_t)(b*NN + tm*64 + wid*16 + li))*1024 + lg*8;
    bf16x8 qf[16];
    #pragma unroll
    for (int ks = 0; ks < 16; ks++) qf[ks] = *(const bf16x8*)(qrow + ks*32);

    f32x4 acc[8];
    #pragma unroll
    for (int cf = 0; cf < 8; cf++) acc[cf] = (f32x4){0.f,0.f,0.f,0.f};

    auto stageB = [&](short* sb, int kk) {
        #pragma unroll
        for (int j = 0; j < 4; j++) {
            const short* gb = Bbase + (size_t)(j*32 + srow)*1024 + kk*64 + gsl;
            GLOAD16(gb, sb + j*2048 + wid*512);
        }
    };
    auto compute = [&](const short* sb, int kt) {
        #pragma unroll
        for (int ks = 0; ks < 2; ks++) {
            int so = ((ks*4 + lg) ^ (li & 7)) * 8;   // swizzled read slot
            bf16x8 aF = qf[kt*2 + ks];
            #pragma unroll
            for (int cf = 0; cf < 8; cf++) {
                bf16x8 bv = *(const bf16x8*)&sb[(cf*16 + li)*64 + so];
                acc[cf] = MFMA_BF(aF, bv, acc[cf]);
            }
        }
    };

    stageB(B0, 0);
    WAITV0_BAR();
    #pragma unroll 8
    for (int kt = 0; kt < 8; kt++) {
        short* cur = (kt & 1) ? B1 : B0;
        short* nxt = (kt & 1) ? B0 : B1;
        if (kt < 7) {
            stageB(nxt, kt + 1);         // 4 loads in flight across barrier
            WAITV4_BAR();                // cur's 4 landed during prev compute
        } else {
            WAITV0_BAR();
        }
        compute(cur, kt);
        PLAIN_BAR();                     // cur reads done before its overwrite
    }

    // epilogue: P' = exp(s-8), rowsum atomics (fixed-shift, validated r5-r15)
    _Float16* Sb = S + ((size_t)b*NN + tm*64 + wid*16)*NN + tn*128;
    float psum[4] = {0.f, 0.f, 0.f, 0.f};
    #pragma unroll
    for (int cf = 0; cf < 8; cf++)
        #pragma unroll
        for (int rr = 0; rr < 4; rr++) {
            float p = exp2f((acc[cf][rr] - 8.f) * LOG2E_);
            p = fminf(p, 60000.f);
            Sb[(size_t)(lg*4 + rr)*NN + cf*16 + li] = (_Float16)p;
            psum[rr] += p;
        }
    #pragma unroll
    for (int rr = 0; rr < 4; rr++) {
        float s = psum[rr];
        s += __shfl_xor(s, 1);
        s += __shfl_xor(s, 2);
        s += __shfl_xor(s, 4);
        s += __shfl_xor(s, 8);
        if (li == 0)
            atomicAdd(&rowsum[b*NN + tm*64 + wid*16 + lg*4 + rr], s);
    }
}

// ---------------------------------------------------------------------------
// K3c: O^T = V^T P'^T (f16 MFMA), normalized by rowsum in the epilogue.
// m97 single-buffer + involution swizzle. Output f16 [ch][q], BN layout.
// launch_bounds (256,3) — verified no-spill (VGPR 60). UNCHANGED.
// ---------------------------------------------------------------------------
__global__ __launch_bounds__(256, 3) void pv_gemm(
    const short* __restrict__ Vt, const _Float16* __restrict__ P,
    const float* __restrict__ rowsum, _Float16* __restrict__ Ot)
{
    __shared__ short ldsA[128*64];
    __shared__ short ldsB[128*64];
    int bi = blockIdx.x;
    int b  = bi & 7;
    int t  = bi >> 3;
    int tm = t & 3, tn = t >> 2;          // tm: ch-tile (0..3), tn: q-tile (0..17)
    int ri = tm >> 1;
    int c0 = (tm & 1) * 128;
    const short*    Apanel = Vt + ((size_t)((ri*NB + b)*NC) + c0)*NN;
    const _Float16* Bpanel = P  + ((size_t)b*NN + tn*128)*NN;
    int tid  = threadIdx.x;
    int lane = tid & 63, wid = tid >> 6;
    int li = lane & 15, lg = lane >> 4;
    int wr = wid >> 1, wc = wid & 1;
    int srow = tid >> 3, schk = tid & 7;
    int gsl = (schk ^ (srow & 7)) * 8;

    f32x4 acc[4][4];
    #pragma unroll
    for (int i = 0; i < 4; i++)
        #pragma unroll
        for (int j = 0; j < 4; j++) acc[i][j] = (f32x4){0.f,0.f,0.f,0.f};

    for (int ms = 0; ms < 36; ms++) {
        #pragma unroll
        for (int j = 0; j < 4; j++) {
            const short*    ga = Apanel + (size_t)(j*32 + srow)*NN + ms*64 + gsl;
            const _Float16* gb = Bpanel + (size_t)(j*32 + srow)*NN + ms*64 + gsl;
            GLOAD16(ga, ldsA + j*2048 + wid*512);
            GLOAD16(gb, ldsB + j*2048 + wid*512);
        }
        __syncthreads();
        #pragma unroll
        for (int ks = 0; ks < 2; ks++) {
            int so = ((ks*4 + lg) ^ (li & 7)) * 8;
            f16x8 a[4], bv[4];
            #pragma unroll
            for (int i = 0; i < 4; i++) {
                a[i]  = *(const f16x8*)&ldsA[(wr*64 + i*16 + li)*64 + so];
                bv[i] = *(const f16x8*)&ldsB[(wc*64 + i*16 + li)*64 + so];
            }
            #pragma unroll
            for (int i = 0; i < 4; i++)
                #pragma unroll
                for (int j = 0; j < 4; j++)
                    acc[i][j] = MFMA_F16(a[i], bv[j], acc[i][j]);
        }
        __syncthreads();
    }

    float linv[4];
    #pragma unroll
    for (int bj = 0; bj < 4; bj++)
        linv[bj] = 1.f / rowsum[b*NN + tn*128 + wc*64 + bj*16 + li];

    _Float16* Ob = Ot + ((size_t)((ri*NB + b)*NC) + c0 + wr*64)*NN + tn*128 + wc*64;
    #pragma unroll
    for (int ai = 0; ai < 4; ai++)
        #pragma unroll
        for (int bj = 0; bj < 4; bj++)
            #pragma unroll
            for (int rr = 0; rr < 4; rr++)
                Ob[(size_t)(ai*16 + lg*4 + rr)*NN + bj*16 + li] =
                    (_Float16)(acc[ai][bj][rr] * linv[bj]);
}

// ---------------------------------------------------------------------------
// K4: BN batch stats per (channel, re/im) over t = x + gamma*O.
// ---------------------------------------------------------------------------
__global__ __launch_bounds__(256) void bn_stats(
    const _Float16* __restrict__ Xbn, const _Float16* __restrict__ Ot,
    const float* __restrict__ gamma_p,
    float* __restrict__ mean_, float* __restrict__ rstd_)
{
    int c = blockIdx.x, g = blockIdx.y;
    int tid = threadIdx.x;
    float gamma = gamma_p[0];
    float s = 0.f, s2 = 0.f;
    for (int it = 0; it < 9; it++) {             // 2304 chunks of 8 per (c,g)
        int chunk = it * 256 + tid;
        int b = chunk / 288, j = chunk - b * 288;
        size_t off = ((size_t)((g * NB + b) * NC + c)) * NN + (size_t)j * 8;
        f16x8 xv = *(const f16x8*)(Xbn + off);
        f16x8 ov = *(const f16x8*)(Ot + off);
        #pragma unroll
        for (int e = 0; e < 8; e++) {
            float t = (float)xv[e] + gamma * (float)ov[e];
            s  += t;
            s2 += t * t;
        }
    }
    #pragma unroll
    for (int mask = 32; mask >= 1; mask >>= 1) {
        s  += __shfl_xor(s, mask);
        s2 += __shfl_xor(s2, mask);
    }
    __shared__ float ls[4], ls2[4];
    int wid = tid >> 6;
    if ((tid & 63) == 0) { ls[wid] = s; ls2[wid] = s2; }
    __syncthreads();
    if (tid == 0) {
        float sum  = ls[0] + ls[1] + ls[2] + ls[3];
        float sum2 = ls2[0] + ls2[1] + ls2[2] + ls2[3];
        float mean = sum * (1.f / 18432.f);
        float var  = sum2 * (1.f / 18432.f) - mean * mean;
        mean_[g * NC + c] = mean;
        rstd_[g * NC + c] = rsqrtf(var + EPS_);
    }
}

// ---------------------------------------------------------------------------
// K5: apply BN, write d_out [2,B,C,H,W] f32. f16 inputs, 8-elem chunks.
// ---------------------------------------------------------------------------
__global__ __launch_bounds__(256) void bn_apply(
    const _Float16* __restrict__ Xbn, const _Float16* __restrict__ Ot,
    const float* __restrict__ gamma_p,
    const float* __restrict__ mean_, const float* __restrict__ rstd_,
    const float* __restrict__ bn_wr, const float* __restrict__ bn_br,
    const float* __restrict__ bn_wi, const float* __restrict__ bn_bi,
    float* __restrict__ out)
{
    size_t i8 = ((size_t)blockIdx.x * 256 + threadIdx.x) * 8;   // grid 4608
    int g = (int)(i8 / ((size_t)NB * NC * NN));
    size_t r1 = i8 - (size_t)g * NB * NC * NN;
    int c = (int)(r1 / NN) & 255;
    float gamma = gamma_p[0];
    f16x8 xv = *(const f16x8*)(Xbn + i8);
    f16x8 ov = *(const f16x8*)(Ot + i8);
    float m = mean_[g * NC + c], rs = rstd_[g * NC + c];
    float w = (g ? bn_wi : bn_wr)[c], bb = (g ? bn_bi : bn_br)[c];
    float a = rs * w;
    float y[8];
    #pragma unroll
    for (int e = 0; e < 8; e++)
        y[e] = ((float)xv[e] + gamma * (float)ov[e] - m) * a + bb;
    float4 y0 = {y[0], y[1], y[2], y[3]};
    float4 y1 = {y[4], y[5], y[6], y[7]};
    *(float4*)(out + i8)     = y0;
    *(float4*)(out + i8 + 4) = y1;
}

// ---------------------------------------------------------------------------
extern "C" void kernel_launch(void* const* d_in, const int* in_sizes, int n_in,
                              void* d_out, int out_size, void* d_ws, size_t ws_size,
                              hipStream_t stream)
{
    const float* xr   = (const float*)d_in[0];
    const float* xi   = (const float*)d_in[1];
    const float* q_wr = (const float*)d_in[2];
    const float* q_wi = (const float*)d_in[3];
    const float* q_br = (const float*)d_in[4];
    const float* q_bi = (const float*)d_in[5];
    const float* k_wr = (const float*)d_in[6];
    const float* k_wi = (const float*)d_in[7];
    const float* k_br = (const float*)d_in[8];
    const float* k_bi = (const float*)d_in[9];
    const float* v_wr = (const float*)d_in[10];
    const float* v_wi = (const float*)d_in[11];
    const float* v_br = (const float*)d_in[12];
    const float* v_bi = (const float*)d_in[13];
    const float* gamma = (const float*)d_in[14];
    const float* bn_wr = (const float*)d_in[15];
    const float* bn_br = (const float*)d_in[16];
    const float* bn_wi = (const float*)d_in[17];
    const float* bn_bi = (const float*)d_in[18];
    float* out = (float*)d_out;

    char* p = (char*)d_ws;
    auto take = [&](size_t bytes) { char* q = p; p += (bytes + 255) & ~(size_t)255; return q; };
    short* Xcat    = (short*)take((size_t)NM * 512 * 2);            // 18.9 MB
    short* Wcat    = (short*)take((size_t)1536 * 512 * 2);          // 1.6 MB
    float* biasc   = (float*)take(1536 * 4);
    short* QK      = (short*)take((size_t)NM * 1024 * 2);           // 37.7 MB
    short* Vt      = (short*)take((size_t)2 * NB * NC * NN * 2);    // 18.9 MB
    _Float16* Ot   = (_Float16*)take((size_t)2 * NB * NC * NN * 2); // 18.9 MB
    _Float16* Xbn  = (_Float16*)take((size_t)2 * NB * NC * NN * 2); // 18.9 MB
    float* mean_   = (float*)take(512 * 4);
    float* rstd_   = (float*)take(512 * 4);
    _Float16* S    = (_Float16*)take((size_t)NB * NN * NN * 2);     // 84.9 MB
    float* rowsum  = (float*)take((size_t)NM * 4);
    (void)ws_size; (void)in_sizes; (void)n_in; (void)out_size;

    head_kernel<<<12360, 256, 0, stream>>>(xr, xi,
                                           q_wr, q_wi, q_br, q_bi,
                                           k_wr, k_wi, k_br, k_bi,
                                           v_wr, v_wi, v_br, v_bi,
                                           Wcat, biasc, Xcat, Xbn, rowsum);
    qkv_gemm<<<dim3(144, 12), 256, 0, stream>>>(Xcat, Wcat, biasc, QK, Vt);
    qk_gemm<<<36*18*8, 256, 0, stream>>>(QK, S, rowsum);
    pv_gemm<<<4*18*8, 256, 0, stream>>>(Vt, S, rowsum, Ot);
    bn_stats<<<dim3(256, 2), dim3(256), 0, stream>>>(Xbn, Ot, gamma, mean_, rstd_);
    bn_apply<<<4608, 256, 0, stream>>>(Xbn, Ot, gamma, mean_, rstd_,
                                       bn_wr, bn_br, bn_wi, bn_bi, out);
}

// Round 17
// 211.014 us; speedup vs baseline: 1.1239x; 1.1239x over previous
//
#include <hip/hip_runtime.h>
#include <cstdint>

#define NB 8
#define NC 256
#define NN 2304           // H*W
#define NM (NB*NN)        // 18432
#define EPS_ 1e-5f
#define LOG2E_ 1.44269504088896f

typedef __attribute__((ext_vector_type(8))) short bf16x8;
typedef __attribute__((ext_vector_type(8))) _Float16 f16x8;
typedef __attribute__((ext_vector_type(4))) _Float16 f16x4;
typedef __attribute__((ext_vector_type(4))) float f32x4;

__device__ __forceinline__ short f2bf(float x) {
    union { float f; uint32_t u; } v; v.f = x;
    uint32_t r = v.u + 0x7fffu + ((v.u >> 16) & 1u);   // RNE
    return (short)(r >> 16);
}

#define MFMA_BF(a,b,c)  __builtin_amdgcn_mfma_f32_16x16x32_bf16(a,b,c,0,0,0)
#define MFMA_F16(a,b,c) __builtin_amdgcn_mfma_f32_16x16x32_f16(a,b,c,0,0,0)

// async global->LDS, 16B per lane; lds ptr must be wave-uniform base
#define GLOAD16(g,l) __builtin_amdgcn_global_load_lds( \
    (__attribute__((address_space(1))) void*)(g), \
    (__attribute__((address_space(3))) void*)(l), 16, 0, 0)

// ---------------------------------------------------------------------------
// K_head: fused independent preprocessing (one dispatch, flat grid):
//   blocks [0, 9216)        : xpose_cast  (x f32 -> Xcat bf16 + Xbn f16)
//   blocks [9216, 12288)    : prepack     (weights -> Wcat bf16, biasc)
//   blocks [12288, 12360)   : zero rowsum (replay-safe)
// ---------------------------------------------------------------------------
__global__ __launch_bounds__(256) void head_kernel(
    const float* __restrict__ xr, const float* __restrict__ xi,
    const float* __restrict__ q_wr, const float* __restrict__ q_wi,
    const float* __restrict__ q_br, const float* __restrict__ q_bi,
    const float* __restrict__ k_wr, const float* __restrict__ k_wi,
    const float* __restrict__ k_br, const float* __restrict__ k_bi,
    const float* __restrict__ v_wr, const float* __restrict__ v_wi,
    const float* __restrict__ v_br, const float* __restrict__ v_bi,
    short* __restrict__ Wcat, float* __restrict__ biasc,
    short* __restrict__ Xcat, _Float16* __restrict__ Xbn,
    float* __restrict__ rowsum)
{
    __shared__ float t[32][33];
    int bid = blockIdx.x;
    int tid = threadIdx.x;
    if (bid < 9216) {
        int bx = bid % 72, rest = bid / 72;
        int by = rest & 7, bz = rest >> 3;
        int ri = bz & 1, b = bz >> 1;
        const float* src = (ri ? xi : xr) + (size_t)b * NC * NN;
        _Float16* xbdst = Xbn + (size_t)(ri * NB + b) * NC * NN;
        int n0 = bx * 32, c0 = by * 32;
        int tx = tid & 31, ty = tid >> 5;       // (32, 8)
        #pragma unroll
        for (int i = 0; i < 4; i++) {
            int c = c0 + ty + i*8;
            float v = src[(size_t)c * NN + n0 + tx];
            t[ty + i*8][tx] = v;
            xbdst[(size_t)c * NN + n0 + tx] = (_Float16)v;
        }
        __syncthreads();
        #pragma unroll
        for (int i = 0; i < 4; i++) {
            int n = n0 + ty + i*8;
            Xcat[(size_t)(b * NN + n) * 512 + ri * 256 + c0 + tx] = f2bf(t[tx][ty + i*8]);
        }
    } else if (bid < 12288) {
        int idx = (bid - 9216) * 256 + tid;     // < 786432
        int g    = idx >> 17;
        int r    = idx & 131071;
        int d    = r >> 9;
        int k    = r & 511;
        int half = k >> 8;
        int kk   = k & 255;
        const float* wr_ = (g < 2) ? q_wr : (g < 4) ? k_wr : v_wr;
        const float* wi_ = (g < 2) ? q_wi : (g < 4) ? k_wi : v_wi;
        bool isR = (g & 1) == 0;
        const float* src = (half == 0) ? (isR ? wr_ : wi_) : (isR ? wi_ : wr_);
        float sign  = (half == 1 && isR) ? -1.f : 1.f;
        float scale = (g < 2) ? 0.0625f : 1.f;
        Wcat[idx] = f2bf(sign * scale * src[d * 256 + kk]);
        if (idx < 1536) {
            int gg = idx >> 8, dd = idx & 255;
            const float* bsrc = (gg==0)?q_br:(gg==1)?q_bi:(gg==2)?k_br:(gg==3)?k_bi:(gg==4)?v_br:v_bi;
            biasc[idx] = bsrc[dd] * ((gg < 2) ? 0.0625f : 1.f);
        }
    } else {
        int i = (bid - 12288) * 256 + tid;
        if (i < NM) rowsum[i] = 0.f;
    }
}

// ---------------------------------------------------------------------------
// K2: QKV GEMM [M x 512] @ [512 x 1536], m97 structure + involution swizzle
// (conflicts=0). launch_bounds (256,3) — verified no-spill config (VGPR 64).
// ---------------------------------------------------------------------------
__global__ __launch_bounds__(256, 3) void qkv_gemm(
    const short* __restrict__ Xcat, const short* __restrict__ Wcat,
    const float* __restrict__ biasc,
    short* __restrict__ QK, short* __restrict__ Vt)
{
    __shared__ short ldsA[128*64];
    __shared__ short ldsB[128*64];
    int tm = blockIdx.x;                 // 0..143 (M tiles)
    int tn = blockIdx.y;                 // 0..11  (N tiles)
    const short* Apanel = Xcat + (size_t)tm * 128 * 512;
    const short* Bpanel = Wcat + (size_t)tn * 128 * 512;
    int tid  = threadIdx.x;
    int lane = tid & 63, wid = tid >> 6;
    int li = lane & 15, lg = lane >> 4;
    int wr = wid >> 1, wc = wid & 1;
    int srow = tid >> 3, schk = tid & 7;
    int gsl = (schk ^ (srow & 7)) * 8;   // pre-swizzled global source slot

    f32x4 acc[4][4];
    #pragma unroll
    for (int i = 0; i < 4; i++)
        #pragma unroll
        for (int j = 0; j < 4; j++) acc[i][j] = (f32x4){0.f,0.f,0.f,0.f};

    for (int ks0 = 0; ks0 < 8; ks0++) {
        #pragma unroll
        for (int j = 0; j < 4; j++) {
            const short* ga = Apanel + (size_t)(j*32 + srow)*512 + ks0*64 + gsl;
            const short* gb = Bpanel + (size_t)(j*32 + srow)*512 + ks0*64 + gsl;
            GLOAD16(ga, ldsA + j*2048 + wid*512);
            GLOAD16(gb, ldsB + j*2048 + wid*512);
        }
        __syncthreads();
        #pragma unroll
        for (int ks = 0; ks < 2; ks++) {
            int so = ((ks*4 + lg) ^ (li & 7)) * 8;   // swizzled read slot
            bf16x8 a[4], bv[4];
            #pragma unroll
            for (int i = 0; i < 4; i++) {
                a[i]  = *(const bf16x8*)&ldsA[(wr*64 + i*16 + li)*64 + so];
                bv[i] = *(const bf16x8*)&ldsB[(wc*64 + i*16 + li)*64 + so];
            }
            #pragma unroll
            for (int i = 0; i < 4; i++)
                #pragma unroll
                for (int j = 0; j < 4; j++)
                    acc[i][j] = MFMA_BF(a[i], bv[j], acc[i][j]);
        }
        __syncthreads();
    }

    if (tn < 8) {
        #pragma unroll
        for (int bj = 0; bj < 4; bj++) {
            int ncol = tn*128 + wc*64 + bj*16 + li;
            float bias = biasc[ncol];
            #pragma unroll
            for (int ai = 0; ai < 4; ai++)
                #pragma unroll
                for (int rr = 0; rr < 4; rr++) {
                    int m = tm*128 + wr*64 + ai*16 + lg*4 + rr;
                    QK[(size_t)m * 1024 + ncol] = f2bf(acc[ai][bj][rr] + bias);
                }
        }
    } else {
        int b  = tm / 18;
        int n0 = (tm - b*18) * 128 + wr*64;
        #pragma unroll
        for (int bj = 0; bj < 4; bj++) {
            int ncol = tn*128 + wc*64 + bj*16 + li;
            int cc = ncol - 1024;        // 0..511
            int ri2 = cc >> 8, c = cc & 255;
            float bias = biasc[ncol];
            short* vrow = Vt + ((size_t)((ri2*NB + b)*NC + c))*NN + n0;
            #pragma unroll
            for (int ai = 0; ai < 4; ai++) {
                f16x4 pk;
                #pragma unroll
                for (int rr = 0; rr < 4; rr++) pk[rr] = (_Float16)(acc[ai][bj][rr] + bias);
                *(f16x4*)(vrow + ai*16 + lg*4) = pk;
            }
        }
    }
}

// ---------------------------------------------------------------------------
// K3a: P' = exp(Q K^T - 8) (f16, unnormalized) + f32 rowsum atomics.
// Fixed-shift softmax (validated r5-r15). m97 single-buffer + involution
// swizzle. launch_bounds (256,3) — verified no-spill (VGPR 68).
// REVERTED to the banked 211-µs form (r16 register-A redesign regressed:
// compiler sank the Q preload into the loop, VGPR 56, qk 71->96 µs).
// ---------------------------------------------------------------------------
__global__ __launch_bounds__(256, 3) void qk_gemm(
    const short* __restrict__ QK, _Float16* __restrict__ S,
    float* __restrict__ rowsum)
{
    __shared__ short ldsA[128*64];
    __shared__ short ldsB[128*64];
    int bi = blockIdx.x;
    int b  = bi & 7;
    int t  = bi >> 3;
    int tm = t % 18, tn = t / 18;
    const short* Abase = QK + ((size_t)b*NN + tm*128)*1024;        // Q cols
    const short* Bbase = QK + ((size_t)b*NN + tn*128)*1024 + 512;  // K cols
    int tid  = threadIdx.x;
    int lane = tid & 63, wid = tid >> 6;
    int li = lane & 15, lg = lane >> 4;
    int wr = wid >> 1, wc = wid & 1;
    int srow = tid >> 3, schk = tid & 7;
    int gsl = (schk ^ (srow & 7)) * 8;

    f32x4 acc[4][4];
    #pragma unroll
    for (int i = 0; i < 4; i++)
        #pragma unroll
        for (int j = 0; j < 4; j++) acc[i][j] = (f32x4){0.f,0.f,0.f,0.f};

    for (int ks0 = 0; ks0 < 8; ks0++) {
        #pragma unroll
        for (int j = 0; j < 4; j++) {
            const short* ga = Abase + (size_t)(j*32 + srow)*1024 + ks0*64 + gsl;
            const short* gb = Bbase + (size_t)(j*32 + srow)*1024 + ks0*64 + gsl;
            GLOAD16(ga, ldsA + j*2048 + wid*512);
            GLOAD16(gb, ldsB + j*2048 + wid*512);
        }
        __syncthreads();
        #pragma unroll
        for (int ks = 0; ks < 2; ks++) {
            int so = ((ks*4 + lg) ^ (li & 7)) * 8;
            bf16x8 a[4], bv[4];
            #pragma unroll
            for (int i = 0; i < 4; i++) {
                a[i]  = *(const bf16x8*)&ldsA[(wr*64 + i*16 + li)*64 + so];
                bv[i] = *(const bf16x8*)&ldsB[(wc*64 + i*16 + li)*64 + so];
            }
            #pragma unroll
            for (int i = 0; i < 4; i++)
                #pragma unroll
                for (int j = 0; j < 4; j++)
                    acc[i][j] = MFMA_BF(a[i], bv[j], acc[i][j]);
        }
        __syncthreads();
    }

    _Float16* Sb = S + ((size_t)b*NN + tm*128 + wr*64)*NN + tn*128 + wc*64;
    float psum[4][4];
    #pragma unroll
    for (int ai = 0; ai < 4; ai++)
        #pragma unroll
        for (int rr = 0; rr < 4; rr++) psum[ai][rr] = 0.f;
    #pragma unroll
    for (int ai = 0; ai < 4; ai++)
        #pragma unroll
        for (int bj = 0; bj < 4; bj++)
            #pragma unroll
            for (int rr = 0; rr < 4; rr++) {
                float p = exp2f((acc[ai][bj][rr] - 8.f) * LOG2E_);
                p = fminf(p, 60000.f);
                Sb[(size_t)(ai*16 + lg*4 + rr)*NN + bj*16 + li] = (_Float16)p;
                psum[ai][rr] += p;
            }
    #pragma unroll
    for (int ai = 0; ai < 4; ai++)
        #pragma unroll
        for (int rr = 0; rr < 4; rr++) {
            float s = psum[ai][rr];
            s += __shfl_xor(s, 1);
            s += __shfl_xor(s, 2);
            s += __shfl_xor(s, 4);
            s += __shfl_xor(s, 8);
            if (li == 0)
                atomicAdd(&rowsum[b*NN + tm*128 + wr*64 + ai*16 + lg*4 + rr], s);
        }
}

// ---------------------------------------------------------------------------
// K3c: O^T = V^T P'^T (f16 MFMA), normalized by rowsum in the epilogue.
// m97 single-buffer + involution swizzle. Output f16 [ch][q], BN layout.
// launch_bounds (256,3) — verified no-spill (VGPR 60).
// ---------------------------------------------------------------------------
__global__ __launch_bounds__(256, 3) void pv_gemm(
    const short* __restrict__ Vt, const _Float16* __restrict__ P,
    const float* __restrict__ rowsum, _Float16* __restrict__ Ot)
{
    __shared__ short ldsA[128*64];
    __shared__ short ldsB[128*64];
    int bi = blockIdx.x;
    int b  = bi & 7;
    int t  = bi >> 3;
    int tm = t & 3, tn = t >> 2;          // tm: ch-tile (0..3), tn: q-tile (0..17)
    int ri = tm >> 1;
    int c0 = (tm & 1) * 128;
    const short*    Apanel = Vt + ((size_t)((ri*NB + b)*NC) + c0)*NN;
    const _Float16* Bpanel = P  + ((size_t)b*NN + tn*128)*NN;
    int tid  = threadIdx.x;
    int lane = tid & 63, wid = tid >> 6;
    int li = lane & 15, lg = lane >> 4;
    int wr = wid >> 1, wc = wid & 1;
    int srow = tid >> 3, schk = tid & 7;
    int gsl = (schk ^ (srow & 7)) * 8;

    f32x4 acc[4][4];
    #pragma unroll
    for (int i = 0; i < 4; i++)
        #pragma unroll
        for (int j = 0; j < 4; j++) acc[i][j] = (f32x4){0.f,0.f,0.f,0.f};

    for (int ms = 0; ms < 36; ms++) {
        #pragma unroll
        for (int j = 0; j < 4; j++) {
            const short*    ga = Apanel + (size_t)(j*32 + srow)*NN + ms*64 + gsl;
            const _Float16* gb = Bpanel + (size_t)(j*32 + srow)*NN + ms*64 + gsl;
            GLOAD16(ga, ldsA + j*2048 + wid*512);
            GLOAD16(gb, ldsB + j*2048 + wid*512);
        }
        __syncthreads();
        #pragma unroll
        for (int ks = 0; ks < 2; ks++) {
            int so = ((ks*4 + lg) ^ (li & 7)) * 8;
            f16x8 a[4], bv[4];
            #pragma unroll
            for (int i = 0; i < 4; i++) {
                a[i]  = *(const f16x8*)&ldsA[(wr*64 + i*16 + li)*64 + so];
                bv[i] = *(const f16x8*)&ldsB[(wc*64 + i*16 + li)*64 + so];
            }
            #pragma unroll
            for (int i = 0; i < 4; i++)
                #pragma unroll
                for (int j = 0; j < 4; j++)
                    acc[i][j] = MFMA_F16(a[i], bv[j], acc[i][j]);
        }
        __syncthreads();
    }

    float linv[4];
    #pragma unroll
    for (int bj = 0; bj < 4; bj++)
        linv[bj] = 1.f / rowsum[b*NN + tn*128 + wc*64 + bj*16 + li];

    _Float16* Ob = Ot + ((size_t)((ri*NB + b)*NC) + c0 + wr*64)*NN + tn*128 + wc*64;
    #pragma unroll
    for (int ai = 0; ai < 4; ai++)
        #pragma unroll
        for (int bj = 0; bj < 4; bj++)
            #pragma unroll
            for (int rr = 0; rr < 4; rr++)
                Ob[(size_t)(ai*16 + lg*4 + rr)*NN + bj*16 + li] =
                    (_Float16)(acc[ai][bj][rr] * linv[bj]);
}

// ---------------------------------------------------------------------------
// K4: BN batch stats per (channel, re/im) over t = x + gamma*O.
// ---------------------------------------------------------------------------
__global__ __launch_bounds__(256) void bn_stats(
    const _Float16* __restrict__ Xbn, const _Float16* __restrict__ Ot,
    const float* __restrict__ gamma_p,
    float* __restrict__ mean_, float* __restrict__ rstd_)
{
    int c = blockIdx.x, g = blockIdx.y;
    int tid = threadIdx.x;
    float gamma = gamma_p[0];
    float s = 0.f, s2 = 0.f;
    for (int it = 0; it < 9; it++) {             // 2304 chunks of 8 per (c,g)
        int chunk = it * 256 + tid;
        int b = chunk / 288, j = chunk - b * 288;
        size_t off = ((size_t)((g * NB + b) * NC + c)) * NN + (size_t)j * 8;
        f16x8 xv = *(const f16x8*)(Xbn + off);
        f16x8 ov = *(const f16x8*)(Ot + off);
        #pragma unroll
        for (int e = 0; e < 8; e++) {
            float t = (float)xv[e] + gamma * (float)ov[e];
            s  += t;
            s2 += t * t;
        }
    }
    #pragma unroll
    for (int mask = 32; mask >= 1; mask >>= 1) {
        s  += __shfl_xor(s, mask);
        s2 += __shfl_xor(s2, mask);
    }
    __shared__ float ls[4], ls2[4];
    int wid = tid >> 6;
    if ((tid & 63) == 0) { ls[wid] = s; ls2[wid] = s2; }
    __syncthreads();
    if (tid == 0) {
        float sum  = ls[0] + ls[1] + ls[2] + ls[3];
        float sum2 = ls2[0] + ls2[1] + ls2[2] + ls2[3];
        float mean = sum * (1.f / 18432.f);
        float var  = sum2 * (1.f / 18432.f) - mean * mean;
        mean_[g * NC + c] = mean;
        rstd_[g * NC + c] = rsqrtf(var + EPS_);
    }
}

// ---------------------------------------------------------------------------
// K5: apply BN, write d_out [2,B,C,H,W] f32. f16 inputs, 8-elem chunks.
// ---------------------------------------------------------------------------
__global__ __launch_bounds__(256) void bn_apply(
    const _Float16* __restrict__ Xbn, const _Float16* __restrict__ Ot,
    const float* __restrict__ gamma_p,
    const float* __restrict__ mean_, const float* __restrict__ rstd_,
    const float* __restrict__ bn_wr, const float* __restrict__ bn_br,
    const float* __restrict__ bn_wi, const float* __restrict__ bn_bi,
    float* __restrict__ out)
{
    size_t i8 = ((size_t)blockIdx.x * 256 + threadIdx.x) * 8;   // grid 4608
    int g = (int)(i8 / ((size_t)NB * NC * NN));
    size_t r1 = i8 - (size_t)g * NB * NC * NN;
    int c = (int)(r1 / NN) & 255;
    float gamma = gamma_p[0];
    f16x8 xv = *(const f16x8*)(Xbn + i8);
    f16x8 ov = *(const f16x8*)(Ot + i8);
    float m = mean_[g * NC + c], rs = rstd_[g * NC + c];
    float w = (g ? bn_wi : bn_wr)[c], bb = (g ? bn_bi : bn_br)[c];
    float a = rs * w;
    float y[8];
    #pragma unroll
    for (int e = 0; e < 8; e++)
        y[e] = ((float)xv[e] + gamma * (float)ov[e] - m) * a + bb;
    float4 y0 = {y[0], y[1], y[2], y[3]};
    float4 y1 = {y[4], y[5], y[6], y[7]};
    *(float4*)(out + i8)     = y0;
    *(float4*)(out + i8 + 4) = y1;
}

// ---------------------------------------------------------------------------
extern "C" void kernel_launch(void* const* d_in, const int* in_sizes, int n_in,
                              void* d_out, int out_size, void* d_ws, size_t ws_size,
                              hipStream_t stream)
{
    const float* xr   = (const float*)d_in[0];
    const float* xi   = (const float*)d_in[1];
    const float* q_wr = (const float*)d_in[2];
    const float* q_wi = (const float*)d_in[3];
    const float* q_br = (const float*)d_in[4];
    const float* q_bi = (const float*)d_in[5];
    const float* k_wr = (const float*)d_in[6];
    const float* k_wi = (const float*)d_in[7];
    const float* k_br = (const float*)d_in[8];
    const float* k_bi = (const float*)d_in[9];
    const float* v_wr = (const float*)d_in[10];
    const float* v_wi = (const float*)d_in[11];
    const float* v_br = (const float*)d_in[12];
    const float* v_bi = (const float*)d_in[13];
    const float* gamma = (const float*)d_in[14];
    const float* bn_wr = (const float*)d_in[15];
    const float* bn_br = (const float*)d_in[16];
    const float* bn_wi = (const float*)d_in[17];
    const float* bn_bi = (const float*)d_in[18];
    float* out = (float*)d_out;

    char* p = (char*)d_ws;
    auto take = [&](size_t bytes) { char* q = p; p += (bytes + 255) & ~(size_t)255; return q; };
    short* Xcat    = (short*)take((size_t)NM * 512 * 2);            // 18.9 MB
    short* Wcat    = (short*)take((size_t)1536 * 512 * 2);          // 1.6 MB
    float* biasc   = (float*)take(1536 * 4);
    short* QK      = (short*)take((size_t)NM * 1024 * 2);           // 37.7 MB
    short* Vt      = (short*)take((size_t)2 * NB * NC * NN * 2);    // 18.9 MB
    _Float16* Ot   = (_Float16*)take((size_t)2 * NB * NC * NN * 2); // 18.9 MB
    _Float16* Xbn  = (_Float16*)take((size_t)2 * NB * NC * NN * 2); // 18.9 MB
    float* mean_   = (float*)take(512 * 4);
    float* rstd_   = (float*)take(512 * 4);
    _Float16* S    = (_Float16*)take((size_t)NB * NN * NN * 2);     // 84.9 MB
    float* rowsum  = (float*)take((size_t)NM * 4);
    (void)ws_size; (void)in_sizes; (void)n_in; (void)out_size;

    head_kernel<<<12360, 256, 0, stream>>>(xr, xi,
                                           q_wr, q_wi, q_br, q_bi,
                                           k_wr, k_wi, k_br, k_bi,
                                           v_wr, v_wi, v_br, v_bi,
                                           Wcat, biasc, Xcat, Xbn, rowsum);
    qkv_gemm<<<dim3(144, 12), 256, 0, stream>>>(Xcat, Wcat, biasc, QK, Vt);
    qk_gemm<<<18*18*8, 256, 0, stream>>>(QK, S, rowsum);
    pv_gemm<<<4*18*8, 256, 0, stream>>>(Vt, S, rowsum, Ot);
    bn_stats<<<dim3(256, 2), dim3(256), 0, stream>>>(Xbn, Ot, gamma, mean_, rstd_);
    bn_apply<<<4608, 256, 0, stream>>>(Xbn, Ot, gamma, mean_, rstd_,
                                       bn_wr, bn_br, bn_wi, bn_bi, out);
}

// Round 18
// 206.419 us; speedup vs baseline: 1.1490x; 1.0223x over previous
//
#include <hip/hip_runtime.h>
#include <cstdint>

#define NB 8
#define NC 256
#define NN 2304           // H*W
#define NM (NB*NN)        // 18432
#define EPS_ 1e-5f
#define LOG2E_ 1.44269504088896f

typedef __attribute__((ext_vector_type(8))) short bf16x8;
typedef __attribute__((ext_vector_type(8))) _Float16 f16x8;
typedef __attribute__((ext_vector_type(4))) _Float16 f16x4;
typedef __attribute__((ext_vector_type(4))) float f32x4;

__device__ __forceinline__ short f2bf(float x) {
    union { float f; uint32_t u; } v; v.f = x;
    uint32_t r = v.u + 0x7fffu + ((v.u >> 16) & 1u);   // RNE
    return (short)(r >> 16);
}

#define MFMA_BF(a,b,c)  __builtin_amdgcn_mfma_f32_16x16x32_bf16(a,b,c,0,0,0)
#define MFMA_F16(a,b,c) __builtin_amdgcn_mfma_f32_16x16x32_f16(a,b,c,0,0,0)

// async global->LDS, 16B per lane; lds ptr must be wave-uniform base
#define GLOAD16(g,l) __builtin_amdgcn_global_load_lds( \
    (__attribute__((address_space(1))) void*)(g), \
    (__attribute__((address_space(3))) void*)(l), 16, 0, 0)

// ---------------------------------------------------------------------------
// K_head: fused independent preprocessing (one dispatch, flat grid):
//   blocks [0, 9216)        : xpose_cast  (x f32 -> Xcat bf16 + Xbn f16)
//   blocks [9216, 12288)    : prepack     (weights -> Wcat bf16, biasc)
//   blocks [12288, 12360)   : zero rowsum (replay-safe)
// ---------------------------------------------------------------------------
__global__ __launch_bounds__(256) void head_kernel(
    const float* __restrict__ xr, const float* __restrict__ xi,
    const float* __restrict__ q_wr, const float* __restrict__ q_wi,
    const float* __restrict__ q_br, const float* __restrict__ q_bi,
    const float* __restrict__ k_wr, const float* __restrict__ k_wi,
    const float* __restrict__ k_br, const float* __restrict__ k_bi,
    const float* __restrict__ v_wr, const float* __restrict__ v_wi,
    const float* __restrict__ v_br, const float* __restrict__ v_bi,
    short* __restrict__ Wcat, float* __restrict__ biasc,
    short* __restrict__ Xcat, _Float16* __restrict__ Xbn,
    float* __restrict__ rowsum)
{
    __shared__ float t[32][33];
    int bid = blockIdx.x;
    int tid = threadIdx.x;
    if (bid < 9216) {
        int bx = bid % 72, rest = bid / 72;
        int by = rest & 7, bz = rest >> 3;
        int ri = bz & 1, b = bz >> 1;
        const float* src = (ri ? xi : xr) + (size_t)b * NC * NN;
        _Float16* xbdst = Xbn + (size_t)(ri * NB + b) * NC * NN;
        int n0 = bx * 32, c0 = by * 32;
        int tx = tid & 31, ty = tid >> 5;       // (32, 8)
        #pragma unroll
        for (int i = 0; i < 4; i++) {
            int c = c0 + ty + i*8;
            float v = src[(size_t)c * NN + n0 + tx];
            t[ty + i*8][tx] = v;
            xbdst[(size_t)c * NN + n0 + tx] = (_Float16)v;
        }
        __syncthreads();
        #pragma unroll
        for (int i = 0; i < 4; i++) {
            int n = n0 + ty + i*8;
            Xcat[(size_t)(b * NN + n) * 512 + ri * 256 + c0 + tx] = f2bf(t[tx][ty + i*8]);
        }
    } else if (bid < 12288) {
        int idx = (bid - 9216) * 256 + tid;     // < 786432
        int g    = idx >> 17;
        int r    = idx & 131071;
        int d    = r >> 9;
        int k    = r & 511;
        int half = k >> 8;
        int kk   = k & 255;
        const float* wr_ = (g < 2) ? q_wr : (g < 4) ? k_wr : v_wr;
        const float* wi_ = (g < 2) ? q_wi : (g < 4) ? k_wi : v_wi;
        bool isR = (g & 1) == 0;
        const float* src = (half == 0) ? (isR ? wr_ : wi_) : (isR ? wi_ : wr_);
        float sign  = (half == 1 && isR) ? -1.f : 1.f;
        float scale = (g < 2) ? 0.0625f : 1.f;
        Wcat[idx] = f2bf(sign * scale * src[d * 256 + kk]);
        if (idx < 1536) {
            int gg = idx >> 8, dd = idx & 255;
            const float* bsrc = (gg==0)?q_br:(gg==1)?q_bi:(gg==2)?k_br:(gg==3)?k_bi:(gg==4)?v_br:v_bi;
            biasc[idx] = bsrc[dd] * ((gg < 2) ? 0.0625f : 1.f);
        }
    } else {
        int i = (bid - 12288) * 256 + tid;
        if (i < NM) rowsum[i] = 0.f;
    }
}

// ---------------------------------------------------------------------------
// K2: QKV GEMM [M x 512] @ [512 x 1536], m97 structure + involution swizzle
// (conflicts=0). launch_bounds (256,3) — verified no-spill config (VGPR 64).
// ---------------------------------------------------------------------------
__global__ __launch_bounds__(256, 3) void qkv_gemm(
    const short* __restrict__ Xcat, const short* __restrict__ Wcat,
    const float* __restrict__ biasc,
    short* __restrict__ QK, short* __restrict__ Vt)
{
    __shared__ short ldsA[128*64];
    __shared__ short ldsB[128*64];
    int tm = blockIdx.x;                 // 0..143 (M tiles)
    int tn = blockIdx.y;                 // 0..11  (N tiles)
    const short* Apanel = Xcat + (size_t)tm * 128 * 512;
    const short* Bpanel = Wcat + (size_t)tn * 128 * 512;
    int tid  = threadIdx.x;
    int lane = tid & 63, wid = tid >> 6;
    int li = lane & 15, lg = lane >> 4;
    int wr = wid >> 1, wc = wid & 1;
    int srow = tid >> 3, schk = tid & 7;
    int gsl = (schk ^ (srow & 7)) * 8;   // pre-swizzled global source slot

    f32x4 acc[4][4];
    #pragma unroll
    for (int i = 0; i < 4; i++)
        #pragma unroll
        for (int j = 0; j < 4; j++) acc[i][j] = (f32x4){0.f,0.f,0.f,0.f};

    for (int ks0 = 0; ks0 < 8; ks0++) {
        #pragma unroll
        for (int j = 0; j < 4; j++) {
            const short* ga = Apanel + (size_t)(j*32 + srow)*512 + ks0*64 + gsl;
            const short* gb = Bpanel + (size_t)(j*32 + srow)*512 + ks0*64 + gsl;
            GLOAD16(ga, ldsA + j*2048 + wid*512);
            GLOAD16(gb, ldsB + j*2048 + wid*512);
        }
        __syncthreads();
        #pragma unroll
        for (int ks = 0; ks < 2; ks++) {
            int so = ((ks*4 + lg) ^ (li & 7)) * 8;   // swizzled read slot
            bf16x8 a[4], bv[4];
            #pragma unroll
            for (int i = 0; i < 4; i++) {
                a[i]  = *(const bf16x8*)&ldsA[(wr*64 + i*16 + li)*64 + so];
                bv[i] = *(const bf16x8*)&ldsB[(wc*64 + i*16 + li)*64 + so];
            }
            #pragma unroll
            for (int i = 0; i < 4; i++)
                #pragma unroll
                for (int j = 0; j < 4; j++)
                    acc[i][j] = MFMA_BF(a[i], bv[j], acc[i][j]);
        }
        __syncthreads();
    }

    if (tn < 8) {
        #pragma unroll
        for (int bj = 0; bj < 4; bj++) {
            int ncol = tn*128 + wc*64 + bj*16 + li;
            float bias = biasc[ncol];
            #pragma unroll
            for (int ai = 0; ai < 4; ai++)
                #pragma unroll
                for (int rr = 0; rr < 4; rr++) {
                    int m = tm*128 + wr*64 + ai*16 + lg*4 + rr;
                    QK[(size_t)m * 1024 + ncol] = f2bf(acc[ai][bj][rr] + bias);
                }
        }
    } else {
        int b  = tm / 18;
        int n0 = (tm - b*18) * 128 + wr*64;
        #pragma unroll
        for (int bj = 0; bj < 4; bj++) {
            int ncol = tn*128 + wc*64 + bj*16 + li;
            int cc = ncol - 1024;        // 0..511
            int ri2 = cc >> 8, c = cc & 255;
            float bias = biasc[ncol];
            short* vrow = Vt + ((size_t)((ri2*NB + b)*NC + c))*NN + n0;
            #pragma unroll
            for (int ai = 0; ai < 4; ai++) {
                f16x4 pk;
                #pragma unroll
                for (int rr = 0; rr < 4; rr++) pk[rr] = (_Float16)(acc[ai][bj][rr] + bias);
                *(f16x4*)(vrow + ai*16 + lg*4) = pk;
            }
        }
    }
}

// ---------------------------------------------------------------------------
// K3a: P' = exp(Q K^T - 8) (f16, unnormalized) + f32 rowsum atomics.
// Fixed-shift softmax (validated r5-r17). m97 single-buffer + involution
// swizzle. launch_bounds (256,3) — verified no-spill (VGPR 68).
// ---------------------------------------------------------------------------
__global__ __launch_bounds__(256, 3) void qk_gemm(
    const short* __restrict__ QK, _Float16* __restrict__ S,
    float* __restrict__ rowsum)
{
    __shared__ short ldsA[128*64];
    __shared__ short ldsB[128*64];
    int bi = blockIdx.x;
    int b  = bi & 7;
    int t  = bi >> 3;
    int tm = t % 18, tn = t / 18;
    const short* Abase = QK + ((size_t)b*NN + tm*128)*1024;        // Q cols
    const short* Bbase = QK + ((size_t)b*NN + tn*128)*1024 + 512;  // K cols
    int tid  = threadIdx.x;
    int lane = tid & 63, wid = tid >> 6;
    int li = lane & 15, lg = lane >> 4;
    int wr = wid >> 1, wc = wid & 1;
    int srow = tid >> 3, schk = tid & 7;
    int gsl = (schk ^ (srow & 7)) * 8;

    f32x4 acc[4][4];
    #pragma unroll
    for (int i = 0; i < 4; i++)
        #pragma unroll
        for (int j = 0; j < 4; j++) acc[i][j] = (f32x4){0.f,0.f,0.f,0.f};

    for (int ks0 = 0; ks0 < 8; ks0++) {
        #pragma unroll
        for (int j = 0; j < 4; j++) {
            const short* ga = Abase + (size_t)(j*32 + srow)*1024 + ks0*64 + gsl;
            const short* gb = Bbase + (size_t)(j*32 + srow)*1024 + ks0*64 + gsl;
            GLOAD16(ga, ldsA + j*2048 + wid*512);
            GLOAD16(gb, ldsB + j*2048 + wid*512);
        }
        __syncthreads();
        #pragma unroll
        for (int ks = 0; ks < 2; ks++) {
            int so = ((ks*4 + lg) ^ (li & 7)) * 8;
            bf16x8 a[4], bv[4];
            #pragma unroll
            for (int i = 0; i < 4; i++) {
                a[i]  = *(const bf16x8*)&ldsA[(wr*64 + i*16 + li)*64 + so];
                bv[i] = *(const bf16x8*)&ldsB[(wc*64 + i*16 + li)*64 + so];
            }
            #pragma unroll
            for (int i = 0; i < 4; i++)
                #pragma unroll
                for (int j = 0; j < 4; j++)
                    acc[i][j] = MFMA_BF(a[i], bv[j], acc[i][j]);
        }
        __syncthreads();
    }

    _Float16* Sb = S + ((size_t)b*NN + tm*128 + wr*64)*NN + tn*128 + wc*64;
    float psum[4][4];
    #pragma unroll
    for (int ai = 0; ai < 4; ai++)
        #pragma unroll
        for (int rr = 0; rr < 4; rr++) psum[ai][rr] = 0.f;
    #pragma unroll
    for (int ai = 0; ai < 4; ai++)
        #pragma unroll
        for (int bj = 0; bj < 4; bj++)
            #pragma unroll
            for (int rr = 0; rr < 4; rr++) {
                float p = exp2f((acc[ai][bj][rr] - 8.f) * LOG2E_);
                p = fminf(p, 60000.f);
                Sb[(size_t)(ai*16 + lg*4 + rr)*NN + bj*16 + li] = (_Float16)p;
                psum[ai][rr] += p;
            }
    #pragma unroll
    for (int ai = 0; ai < 4; ai++)
        #pragma unroll
        for (int rr = 0; rr < 4; rr++) {
            float s = psum[ai][rr];
            s += __shfl_xor(s, 1);
            s += __shfl_xor(s, 2);
            s += __shfl_xor(s, 4);
            s += __shfl_xor(s, 8);
            if (li == 0)
                atomicAdd(&rowsum[b*NN + tm*128 + wr*64 + ai*16 + lg*4 + rr], s);
        }
}

// ---------------------------------------------------------------------------
// K3c: O^T = V^T P'^T (f16 MFMA), normalized by rowsum in the epilogue.
// m97 single-buffer + involution swizzle. Output f16 [ch][q], BN layout.
// launch_bounds (256,3) — verified no-spill (VGPR 60).
// ---------------------------------------------------------------------------
__global__ __launch_bounds__(256, 3) void pv_gemm(
    const short* __restrict__ Vt, const _Float16* __restrict__ P,
    const float* __restrict__ rowsum, _Float16* __restrict__ Ot)
{
    __shared__ short ldsA[128*64];
    __shared__ short ldsB[128*64];
    int bi = blockIdx.x;
    int b  = bi & 7;
    int t  = bi >> 3;
    int tm = t & 3, tn = t >> 2;          // tm: ch-tile (0..3), tn: q-tile (0..17)
    int ri = tm >> 1;
    int c0 = (tm & 1) * 128;
    const short*    Apanel = Vt + ((size_t)((ri*NB + b)*NC) + c0)*NN;
    const _Float16* Bpanel = P  + ((size_t)b*NN + tn*128)*NN;
    int tid  = threadIdx.x;
    int lane = tid & 63, wid = tid >> 6;
    int li = lane & 15, lg = lane >> 4;
    int wr = wid >> 1, wc = wid & 1;
    int srow = tid >> 3, schk = tid & 7;
    int gsl = (schk ^ (srow & 7)) * 8;

    f32x4 acc[4][4];
    #pragma unroll
    for (int i = 0; i < 4; i++)
        #pragma unroll
        for (int j = 0; j < 4; j++) acc[i][j] = (f32x4){0.f,0.f,0.f,0.f};

    for (int ms = 0; ms < 36; ms++) {
        #pragma unroll
        for (int j = 0; j < 4; j++) {
            const short*    ga = Apanel + (size_t)(j*32 + srow)*NN + ms*64 + gsl;
            const _Float16* gb = Bpanel + (size_t)(j*32 + srow)*NN + ms*64 + gsl;
            GLOAD16(ga, ldsA + j*2048 + wid*512);
            GLOAD16(gb, ldsB + j*2048 + wid*512);
        }
        __syncthreads();
        #pragma unroll
        for (int ks = 0; ks < 2; ks++) {
            int so = ((ks*4 + lg) ^ (li & 7)) * 8;
            f16x8 a[4], bv[4];
            #pragma unroll
            for (int i = 0; i < 4; i++) {
                a[i]  = *(const f16x8*)&ldsA[(wr*64 + i*16 + li)*64 + so];
                bv[i] = *(const f16x8*)&ldsB[(wc*64 + i*16 + li)*64 + so];
            }
            #pragma unroll
            for (int i = 0; i < 4; i++)
                #pragma unroll
                for (int j = 0; j < 4; j++)
                    acc[i][j] = MFMA_F16(a[i], bv[j], acc[i][j]);
        }
        __syncthreads();
    }

    float linv[4];
    #pragma unroll
    for (int bj = 0; bj < 4; bj++)
        linv[bj] = 1.f / rowsum[b*NN + tn*128 + wc*64 + bj*16 + li];

    _Float16* Ob = Ot + ((size_t)((ri*NB + b)*NC) + c0 + wr*64)*NN + tn*128 + wc*64;
    #pragma unroll
    for (int ai = 0; ai < 4; ai++)
        #pragma unroll
        for (int bj = 0; bj < 4; bj++)
            #pragma unroll
            for (int rr = 0; rr < 4; rr++)
                Ob[(size_t)(ai*16 + lg*4 + rr)*NN + bj*16 + li] =
                    (_Float16)(acc[ai][bj][rr] * linv[bj]);
}

// ---------------------------------------------------------------------------
// K4: FUSED BN (stats + apply in one dispatch). One block per (channel c,
// re/im g). Pass 1: stream the channel's 18432 elems (f16x8), accumulate
// sum/sum^2, block-reduce to mean/rstd in LDS. Pass 2: re-stream (L2-hot,
// ~74 KB/block) and write normalized f32 output. Output offset == input
// offset (both [g][b][c][n]). Pure merge of the two r17 kernels.
// ---------------------------------------------------------------------------
__global__ __launch_bounds__(256) void bn_fused(
    const _Float16* __restrict__ Xbn, const _Float16* __restrict__ Ot,
    const float* __restrict__ gamma_p,
    const float* __restrict__ bn_wr, const float* __restrict__ bn_br,
    const float* __restrict__ bn_wi, const float* __restrict__ bn_bi,
    float* __restrict__ out)
{
    int c = blockIdx.x, g = blockIdx.y;
    int tid = threadIdx.x;
    float gamma = gamma_p[0];
    float s = 0.f, s2 = 0.f;
    for (int it = 0; it < 9; it++) {             // 2304 chunks of 8 per (c,g)
        int chunk = it * 256 + tid;
        int b = chunk / 288, j = chunk - b * 288;
        size_t off = ((size_t)((g * NB + b) * NC + c)) * NN + (size_t)j * 8;
        f16x8 xv = *(const f16x8*)(Xbn + off);
        f16x8 ov = *(const f16x8*)(Ot + off);
        #pragma unroll
        for (int e = 0; e < 8; e++) {
            float t = (float)xv[e] + gamma * (float)ov[e];
            s  += t;
            s2 += t * t;
        }
    }
    #pragma unroll
    for (int mask = 32; mask >= 1; mask >>= 1) {
        s  += __shfl_xor(s, mask);
        s2 += __shfl_xor(s2, mask);
    }
    __shared__ float ls[4], ls2[4];
    __shared__ float smean, srstd;
    int wid = tid >> 6;
    if ((tid & 63) == 0) { ls[wid] = s; ls2[wid] = s2; }
    __syncthreads();
    if (tid == 0) {
        float sum  = ls[0] + ls[1] + ls[2] + ls[3];
        float sum2 = ls2[0] + ls2[1] + ls2[2] + ls2[3];
        float mean = sum * (1.f / 18432.f);
        float var  = sum2 * (1.f / 18432.f) - mean * mean;
        smean = mean;
        srstd = rsqrtf(var + EPS_);
    }
    __syncthreads();
    float m  = smean;
    float a  = srstd * ((g ? bn_wi : bn_wr)[c]);
    float bb = (g ? bn_bi : bn_br)[c];
    for (int it = 0; it < 9; it++) {
        int chunk = it * 256 + tid;
        int b = chunk / 288, j = chunk - b * 288;
        size_t off = ((size_t)((g * NB + b) * NC + c)) * NN + (size_t)j * 8;
        f16x8 xv = *(const f16x8*)(Xbn + off);
        f16x8 ov = *(const f16x8*)(Ot + off);
        float y[8];
        #pragma unroll
        for (int e = 0; e < 8; e++)
            y[e] = ((float)xv[e] + gamma * (float)ov[e] - m) * a + bb;
        float4 y0 = {y[0], y[1], y[2], y[3]};
        float4 y1 = {y[4], y[5], y[6], y[7]};
        *(float4*)(out + off)     = y0;
        *(float4*)(out + off + 4) = y1;
    }
}

// ---------------------------------------------------------------------------
extern "C" void kernel_launch(void* const* d_in, const int* in_sizes, int n_in,
                              void* d_out, int out_size, void* d_ws, size_t ws_size,
                              hipStream_t stream)
{
    const float* xr   = (const float*)d_in[0];
    const float* xi   = (const float*)d_in[1];
    const float* q_wr = (const float*)d_in[2];
    const float* q_wi = (const float*)d_in[3];
    const float* q_br = (const float*)d_in[4];
    const float* q_bi = (const float*)d_in[5];
    const float* k_wr = (const float*)d_in[6];
    const float* k_wi = (const float*)d_in[7];
    const float* k_br = (const float*)d_in[8];
    const float* k_bi = (const float*)d_in[9];
    const float* v_wr = (const float*)d_in[10];
    const float* v_wi = (const float*)d_in[11];
    const float* v_br = (const float*)d_in[12];
    const float* v_bi = (const float*)d_in[13];
    const float* gamma = (const float*)d_in[14];
    const float* bn_wr = (const float*)d_in[15];
    const float* bn_br = (const float*)d_in[16];
    const float* bn_wi = (const float*)d_in[17];
    const float* bn_bi = (const float*)d_in[18];
    float* out = (float*)d_out;

    char* p = (char*)d_ws;
    auto take = [&](size_t bytes) { char* q = p; p += (bytes + 255) & ~(size_t)255; return q; };
    short* Xcat    = (short*)take((size_t)NM * 512 * 2);            // 18.9 MB
    short* Wcat    = (short*)take((size_t)1536 * 512 * 2);          // 1.6 MB
    float* biasc   = (float*)take(1536 * 4);
    short* QK      = (short*)take((size_t)NM * 1024 * 2);           // 37.7 MB
    short* Vt      = (short*)take((size_t)2 * NB * NC * NN * 2);    // 18.9 MB
    _Float16* Ot   = (_Float16*)take((size_t)2 * NB * NC * NN * 2); // 18.9 MB
    _Float16* Xbn  = (_Float16*)take((size_t)2 * NB * NC * NN * 2); // 18.9 MB
    _Float16* S    = (_Float16*)take((size_t)NB * NN * NN * 2);     // 84.9 MB
    float* rowsum  = (float*)take((size_t)NM * 4);
    (void)ws_size; (void)in_sizes; (void)n_in; (void)out_size;

    head_kernel<<<12360, 256, 0, stream>>>(xr, xi,
                                           q_wr, q_wi, q_br, q_bi,
                                           k_wr, k_wi, k_br, k_bi,
                                           v_wr, v_wi, v_br, v_bi,
                                           Wcat, biasc, Xcat, Xbn, rowsum);
    qkv_gemm<<<dim3(144, 12), 256, 0, stream>>>(Xcat, Wcat, biasc, QK, Vt);
    qk_gemm<<<18*18*8, 256, 0, stream>>>(QK, S, rowsum);
    pv_gemm<<<4*18*8, 256, 0, stream>>>(Vt, S, rowsum, Ot);
    bn_fused<<<dim3(256, 2), 256, 0, stream>>>(Xbn, Ot, gamma,
                                               bn_wr, bn_br, bn_wi, bn_bi, out);
}